// Round 1
// baseline (1565.053 us; speedup 1.0000x reference)
//
#include <hip/hip_runtime.h>
#include <hip/hip_bf16.h>
#include <cstdint>

// Model constants
#define B_SZ 128
#define L_SZ 150
#define E_SZ 150
#define HIDN 128
#define M_TOK (B_SZ*L_SZ)   // 19200
#define G3 384              // 3*HID gates

__device__ __forceinline__ float sigm(float x){ return 1.f/(1.f+__expf(-x)); }

// ---------------- kernel 1: c[t][32] = softmax over last-4 of code[x[t]] ----------------
__global__ void softmax_c_kernel(const float* __restrict__ code, const int* __restrict__ x,
                                 float* __restrict__ c){
  int idx = blockIdx.x*blockDim.x + threadIdx.x;
  if (idx >= M_TOK*8) return;
  int t = idx >> 3, j = idx & 7;
  int tok = x[t];
  const float* p = code + ((size_t)tok*32 + j*4);
  float a0=p[0],a1=p[1],a2=p[2],a3=p[3];
  float mx = fmaxf(fmaxf(a0,a1),fmaxf(a2,a3));
  float e0=__expf(a0-mx),e1=__expf(a1-mx),e2=__expf(a2-mx),e3=__expf(a3-mx);
  float inv = 1.f/(e0+e1+e2+e3);
  float* q = c + ((size_t)t*32 + j*4);
  q[0]=e0*inv; q[1]=e1*inv; q[2]=e2*inv; q[3]=e3*inv;
}

// ---------------- kernel 2: emb[t][e] = sum_i c[t][i]*codebook[i][e] ----------------
__global__ void embed_kernel(const float* __restrict__ c, const float* __restrict__ cb,
                             float* __restrict__ emb){
  int idx = blockIdx.x*blockDim.x + threadIdx.x;
  if (idx >= M_TOK*E_SZ) return;
  int t = idx / E_SZ; int e = idx - t*E_SZ;
  const float* cr = c + (size_t)t*32;
  float acc = 0.f;
  #pragma unroll
  for (int i=0;i<32;i++) acc += cr[i]*cb[i*E_SZ + e];
  emb[idx] = acc;
}

// ---------------- kernel 3: gi[dir][m][384] = A[m][K] . W[dir*384+g][K] + bias ----------------
__global__ __launch_bounds__(256) void gemm_gi_kernel(
    const float* __restrict__ A, const float* __restrict__ W,
    const float* __restrict__ bias, float* __restrict__ out, int K)
{
  __shared__ float As[16][64];
  __shared__ float Bs[16][64];
  int m0 = blockIdx.y*64, n0 = blockIdx.x*64;
  int tid = threadIdx.x;
  int ty = tid>>4, tx = tid&15;
  int r = tid>>2, kq = (tid&3)*4;
  float acc[4][4] = {{0.f}};
  for (int k0=0;k0<K;k0+=16){
    #pragma unroll
    for (int i=0;i<4;i++){
      int kk = kq+i, k = k0+kk;
      float av=0.f, bv=0.f;
      if (k<K){ av = A[(size_t)(m0+r)*K + k]; bv = W[(size_t)(n0+r)*K + k]; }
      As[kk][r]=av; Bs[kk][r]=bv;
    }
    __syncthreads();
    #pragma unroll
    for (int kk=0;kk<16;kk++){
      float4 a4 = *(const float4*)&As[kk][ty<<2];
      float4 b4 = *(const float4*)&Bs[kk][tx<<2];
      float aa[4]={a4.x,a4.y,a4.z,a4.w}, bb[4]={b4.x,b4.y,b4.z,b4.w};
      #pragma unroll
      for (int i=0;i<4;i++)
        #pragma unroll
        for (int j=0;j<4;j++) acc[i][j] += aa[i]*bb[j];
    }
    __syncthreads();
  }
  #pragma unroll
  for (int j=0;j<4;j++){
    int n = n0 + (tx<<2) + j;
    int dir = (n >= G3) ? 1 : 0; int g = n - dir*G3;
    float bv = bias[n];
    #pragma unroll
    for (int i=0;i<4;i++){
      int mm = m0 + (ty<<2) + i;
      out[((size_t)dir*M_TOK + mm)*G3 + g] = acc[i][j] + bv;
    }
  }
}

// ---------------- kernel 4: GRU scan. grid = 256 blocks (dir*128 + b), 384 threads ----------------
__global__ __launch_bounds__(384) void gru_scan_kernel(
    const float* __restrict__ gi,   // [2][19200][384] (m = b*150+t)
    const float* __restrict__ whh,  // [2][384][128]
    const float* __restrict__ bhh,  // [2][384]
    float* __restrict__ out, int rowStride, int dirOffset)
{
  int bx = blockIdx.x; int dir = bx>>7; int b = bx&127;
  int tid = threadIdx.x;
  __shared__ float s_h[128];
  __shared__ float s_gh[384];
  float4 w[32];
  const float4* wrow = (const float4*)(whh + ((size_t)(dir*G3 + tid))*HIDN);
  #pragma unroll
  for (int i=0;i<32;i++) w[i] = wrow[i];
  float bias = bhh[dir*G3 + tid];
  if (tid < 128) s_h[tid] = 0.f;
  __syncthreads();
  const float* gib = gi + ((size_t)dir*M_TOK + (size_t)b*L_SZ)*G3;
  for (int s=0; s<L_SZ; ++s){
    int t = dir ? (L_SZ-1 - s) : s;
    float acc = bias;
    const float4* h4 = (const float4*)s_h;
    #pragma unroll
    for (int i=0;i<32;i++){
      float4 hv = h4[i];
      acc += w[i].x*hv.x + w[i].y*hv.y + w[i].z*hv.z + w[i].w*hv.w;
    }
    s_gh[tid] = acc;
    __syncthreads();
    if (tid < 128){
      const float* gr = gib + (size_t)t*G3;
      float ir = gr[tid], iz = gr[128+tid], inn = gr[256+tid];
      float hr = s_gh[tid], hz = s_gh[128+tid], hn = s_gh[256+tid];
      float rr = sigm(ir+hr);
      float zz = sigm(iz+hz);
      float xn = inn + rr*hn;
      float e2 = __expf(2.f*xn);
      float nn = 1.f - 2.f/(e2+1.f);   // tanh
      float hnew = (1.f-zz)*nn + zz*s_h[tid];
      s_h[tid] = hnew;
      out[(size_t)(b*L_SZ + t)*rowStride + (size_t)dir*dirOffset + tid] = hnew;
    }
    __syncthreads();
  }
}

// ---------------- kernel 5: out = fwd+bwd, reshape to [b][n=8][t][16], layernorm(16) ----------------
__global__ void ln0_kernel(const float* __restrict__ h2, const float* __restrict__ g,
                           const float* __restrict__ bt, float* __restrict__ out_ln){
  int idx = blockIdx.x*blockDim.x + threadIdx.x;
  if (idx >= B_SZ*8*L_SZ) return;
  int t = idx % L_SZ; int bn = idx / L_SZ; int n = bn & 7; int b = bn >> 3;
  const float* f0 = h2 + (size_t)(b*L_SZ+t)*HIDN + n*16;
  const float* f1 = f0 + (size_t)M_TOK*HIDN;
  float v[16]; float s = 0.f;
  #pragma unroll
  for (int d=0;d<16;d++){ v[d] = f0[d] + f1[d]; s += v[d]; }
  float mu = s*(1.f/16.f);
  float q = 0.f;
  #pragma unroll
  for (int d=0;d<16;d++){ float df = v[d]-mu; q += df*df; }
  float rs = rsqrtf(q*(1.f/16.f) + 1e-5f);
  float* o = out_ln + (size_t)idx*16;
  #pragma unroll
  for (int d=0;d<16;d++) o[d] = (v[d]-mu)*rs*g[d] + bt[d];
}

// ---------------- kernel 6: capsule conv (no-routing) + fused LN ----------------
// in [B][NC][HIN][16]; w [3][NC][4][4][32]; out [B][32][HOUT][16]
__global__ __launch_bounds__(128) void caps_conv_kernel(
    const float* __restrict__ in, const float* __restrict__ w,
    const float* __restrict__ gam, const float* __restrict__ bet,
    float* __restrict__ out, int NC, int HIN, int HOUT, int S, float inv_m)
{
  __shared__ float wc[3*8*512];     // [k][nn][x][d][32] for 8-caps chunk
  __shared__ float in_s[8*9*16];
  int b = blockIdx.y;
  int h0 = blockIdx.x*4;
  int tid = threadIdx.x;
  int m = tid >> 2, d = tid & 3;
  int nrows = 3*S + 3;
  int row0 = h0 * S;
  int nch = NC >> 3;
  float acc[4][4] = {{0.f}};
  for (int ch=0; ch<nch; ++ch){
    int n0 = ch*8;
    for (int i=tid; i<3072; i+=128){
      int k = i/1024, off = i - k*1024;
      ((float4*)wc)[(size_t)k*1024 + off] = ((const float4*)w)[(size_t)(k*NC + n0)*128 + off];
    }
    int tot4 = 8*nrows*4;
    for (int i=tid;i<tot4;i+=128){
      int nn = i/(nrows*4); int rem = i - nn*nrows*4; int rr = rem>>2; int q = rem&3;
      int row = row0 + rr;
      float4 v = make_float4(0.f,0.f,0.f,0.f);
      if (row < HIN) v = ((const float4*)in)[((size_t)(b*NC + n0 + nn)*HIN + row)*4 + q];
      ((float4*)in_s)[(nn*nrows + rr)*4 + q] = v;
    }
    __syncthreads();
    #pragma unroll
    for (int k=0;k<3;k++)
    for (int nn=0;nn<8;nn++)
    #pragma unroll
    for (int xx=0;xx<4;xx++){
      float wv = wc[(((k*8+nn)*4+xx)*4 + d)*32 + m];
      #pragma unroll
      for (int hh=0;hh<4;hh++){
        const float* ip = &in_s[(nn*nrows + hh*S + k)*16 + xx];
        #pragma unroll
        for (int a=0;a<4;a++) acc[hh][a] += wv * ip[a*4];
      }
    }
    __syncthreads();
  }
  float gv[4], bv[4];
  #pragma unroll
  for (int a=0;a<4;a++){ gv[a]=gam[a*4+d]; bv[a]=bet[a*4+d]; }
  for (int hh=0; hh<4; ++hh){
    int h = h0+hh;
    if (h >= HOUT) break;       // uniform across block
    float s = 0.f;
    #pragma unroll
    for (int a=0;a<4;a++){ acc[hh][a] *= inv_m; s += acc[hh][a]; }
    s += __shfl_xor(s,1); s += __shfl_xor(s,2);
    float mu = s*(1.f/16.f);
    float q2 = 0.f;
    #pragma unroll
    for (int a=0;a<4;a++){ float df = acc[hh][a]-mu; q2 += df*df; }
    q2 += __shfl_xor(q2,1); q2 += __shfl_xor(q2,2);
    float rs = rsqrtf(q2*(1.f/16.f) + 1e-5f);
    float* op = out + ((size_t)(b*32+m)*HOUT + h)*16 + d;
    #pragma unroll
    for (int a=0;a<4;a++) op[a*4] = (acc[hh][a]-mu)*rs*gv[a] + bv[a];
  }
}

// ---------------- kernel 7: v3[b][m][16] = LN( (1/15) sum_{n,x} fi*wfc ) ----------------
__global__ __launch_bounds__(256) void v3pre_kernel(
    const float* __restrict__ v2, const float* __restrict__ wfc,
    const float* __restrict__ g, const float* __restrict__ bt, float* __restrict__ v3)
{
  int m = blockIdx.x; int b = blockIdx.y; int tid = threadIdx.x;
  float acc[16];
  #pragma unroll
  for (int i=0;i<16;i++) acc[i]=0.f;
  for (int n = tid; n < 2304; n += 256){
    const float4* fp = (const float4*)(v2 + (size_t)(b*2304 + n)*16);
    float4 f0=fp[0],f1=fp[1],f2=fp[2],f3=fp[3];
    float f[16]={f0.x,f0.y,f0.z,f0.w,f1.x,f1.y,f1.z,f1.w,f2.x,f2.y,f2.z,f2.w,f3.x,f3.y,f3.z,f3.w};
    float wv[16];
    #pragma unroll
    for (int x=0;x<4;x++)
      #pragma unroll
      for (int d=0;d<4;d++) wv[x*4+d] = wfc[(size_t)((n*4+x)*4+d)*15 + m];
    #pragma unroll
    for (int a=0;a<4;a++)
      #pragma unroll
      for (int x=0;x<4;x++){
        float fv = f[a*4+x];
        #pragma unroll
        for (int d=0;d<4;d++) acc[a*4+d] += fv*wv[x*4+d];
      }
  }
  __shared__ float red[4][16];
  int lane = tid&63, wv_ = tid>>6;
  #pragma unroll
  for (int i=0;i<16;i++){
    float v = acc[i];
    v += __shfl_xor(v,1); v += __shfl_xor(v,2); v += __shfl_xor(v,4);
    v += __shfl_xor(v,8); v += __shfl_xor(v,16); v += __shfl_xor(v,32);
    if (lane==0) red[wv_][i] = v;
  }
  __syncthreads();
  if (tid < 16){
    float s = (red[0][tid]+red[1][tid]+red[2][tid]+red[3][tid]) * (1.f/15.f);
    float tot = s; tot += __shfl_xor(tot,1); tot += __shfl_xor(tot,2);
    tot += __shfl_xor(tot,4); tot += __shfl_xor(tot,8);
    float mu = tot*(1.f/16.f);
    float df = s-mu;
    float q = df*df; q += __shfl_xor(q,1); q += __shfl_xor(q,2);
    q += __shfl_xor(q,4); q += __shfl_xor(q,8);
    float rs = rsqrtf(q*(1.f/16.f) + 1e-5f);
    v3[(size_t)(b*15+m)*16 + tid] = df*rs*g[tid] + bt[tid];
  }
}

// ---------------- kernel 8: routing logits -> qk3[b][n][15] ----------------
__global__ __launch_bounds__(256) void qk3_kernel(
    const float* __restrict__ v2, const float* __restrict__ wfc,
    const float* __restrict__ v3, float* __restrict__ qk3)
{
  int b = blockIdx.y; int tid = threadIdx.x;
  int n = blockIdx.x*256 + tid;
  __shared__ float v3s[240];
  if (tid < 240) v3s[tid] = v3[(size_t)b*240 + tid];
  __syncthreads();
  const float4* fp = (const float4*)(v2 + (size_t)(b*2304 + n)*16);
  float4 f0=fp[0],f1=fp[1],f2=fp[2],f3=fp[3];
  float f[16]={f0.x,f0.y,f0.z,f0.w,f1.x,f1.y,f1.z,f1.w,f2.x,f2.y,f2.z,f2.w,f3.x,f3.y,f3.z,f3.w};
  float lg[15];
  for (int m=0;m<15;m++){
    float s = 0.f;
    #pragma unroll
    for (int x=0;x<4;x++)
      #pragma unroll
      for (int d=0;d<4;d++){
        float wv = wfc[(size_t)((n*4+x)*4+d)*15 + m];
        float p = f[x]*v3s[m*16+d] + f[4+x]*v3s[m*16+4+d]
                + f[8+x]*v3s[m*16+8+d] + f[12+x]*v3s[m*16+12+d];
        s += wv*p;
      }
    lg[m] = s*0.25f;
  }
  float mx = lg[0];
  for (int m=1;m<15;m++) mx = fmaxf(mx, lg[m]);
  float se = 0.f;
  for (int m=0;m<15;m++){ lg[m] = __expf(lg[m]-mx); se += lg[m]; }
  float inv = 1.f/se;
  float s2 = 0.f;
  for (int m=0;m<15;m++){ lg[m] *= inv; s2 += lg[m]; }
  float inv2 = 1.f/(s2 + 1e-10f);
  float* qp = qk3 + (size_t)(b*2304 + n)*15;
  for (int m=0;m<15;m++) qp[m] = lg[m]*inv2;
}

// ---------------- kernel 9: nv3 = sum_n qk*fi*wfc ; LN ; out = nrm^2/(1+nrm^2) ----------------
__global__ __launch_bounds__(256) void nv3_out_kernel(
    const float* __restrict__ v2, const float* __restrict__ wfc,
    const float* __restrict__ qk3, const float* __restrict__ g,
    const float* __restrict__ bt, float* __restrict__ out)
{
  int m = blockIdx.x; int b = blockIdx.y; int tid = threadIdx.x;
  float acc[16];
  #pragma unroll
  for (int i=0;i<16;i++) acc[i]=0.f;
  for (int n = tid; n < 2304; n += 256){
    float q = qk3[(size_t)(b*2304+n)*15 + m];
    const float4* fp = (const float4*)(v2 + (size_t)(b*2304 + n)*16);
    float4 f0=fp[0],f1=fp[1],f2=fp[2],f3=fp[3];
    float f[16]={f0.x,f0.y,f0.z,f0.w,f1.x,f1.y,f1.z,f1.w,f2.x,f2.y,f2.z,f2.w,f3.x,f3.y,f3.z,f3.w};
    float wv[16];
    #pragma unroll
    for (int x=0;x<4;x++)
      #pragma unroll
      for (int d=0;d<4;d++) wv[x*4+d] = wfc[(size_t)((n*4+x)*4+d)*15 + m];
    #pragma unroll
    for (int a=0;a<4;a++)
      #pragma unroll
      for (int d=0;d<4;d++){
        float u = f[a*4+0]*wv[0*4+d] + f[a*4+1]*wv[1*4+d] + f[a*4+2]*wv[2*4+d] + f[a*4+3]*wv[3*4+d];
        acc[a*4+d] += q*u;
      }
  }
  __shared__ float red[4][16];
  int lane = tid&63, wv_ = tid>>6;
  #pragma unroll
  for (int i=0;i<16;i++){
    float v = acc[i];
    v += __shfl_xor(v,1); v += __shfl_xor(v,2); v += __shfl_xor(v,4);
    v += __shfl_xor(v,8); v += __shfl_xor(v,16); v += __shfl_xor(v,32);
    if (lane==0) red[wv_][i] = v;
  }
  __syncthreads();
  if (tid < 16){
    float s = red[0][tid]+red[1][tid]+red[2][tid]+red[3][tid];
    float tot = s; tot += __shfl_xor(tot,1); tot += __shfl_xor(tot,2);
    tot += __shfl_xor(tot,4); tot += __shfl_xor(tot,8);
    float mu = tot*(1.f/16.f);
    float df = s-mu;
    float q = df*df; q += __shfl_xor(q,1); q += __shfl_xor(q,2);
    q += __shfl_xor(q,4); q += __shfl_xor(q,8);
    float rs = rsqrtf(q*(1.f/16.f) + 1e-5f);
    float v = df*rs*g[tid] + bt[tid];
    float q2 = v*v; q2 += __shfl_xor(q2,1); q2 += __shfl_xor(q2,2);
    q2 += __shfl_xor(q2,4); q2 += __shfl_xor(q2,8);
    if (tid==0) out[(size_t)b*15 + m] = q2/(1.f+q2);
  }
}

// =================================================================================
extern "C" void kernel_launch(void* const* d_in, const int* in_sizes, int n_in,
                              void* d_out, int out_size, void* d_ws, size_t ws_size,
                              hipStream_t stream) {
  const float* code     = (const float*)d_in[0];
  const float* codebook = (const float*)d_in[1];
  const float* w_ih0    = (const float*)d_in[2];
  const float* w_hh0    = (const float*)d_in[3];
  const float* b_ih0    = (const float*)d_in[4];
  const float* b_hh0    = (const float*)d_in[5];
  const float* w_ih1    = (const float*)d_in[6];
  const float* w_hh1    = (const float*)d_in[7];
  const float* b_ih1    = (const float*)d_in[8];
  const float* b_hh1    = (const float*)d_in[9];
  const float* ln0g     = (const float*)d_in[10];
  const float* ln0b     = (const float*)d_in[11];
  const float* w1       = (const float*)d_in[12];
  const float* ln1g     = (const float*)d_in[13];
  const float* ln1b     = (const float*)d_in[14];
  const float* w2       = (const float*)d_in[15];
  const float* ln2g     = (const float*)d_in[16];
  const float* ln2b     = (const float*)d_in[17];
  const float* wfc      = (const float*)d_in[18];
  const float* lnfg     = (const float*)d_in[19];
  const float* lnfb     = (const float*)d_in[20];
  const int*   x        = (const int*)d_in[21];
  float* out = (float*)d_out;
  float* ws  = (float*)d_ws;

  // workspace layout (floats). total = 27,456,000 f = 109,824,000 B (~105 MiB)
  const size_t OFF_A = 0;             // emb (2,880,000) -> later out_ln (2,457,600)
  const size_t OFF_B = 2880000;       // gi (14,745,600) -> later v1/v2/qk3
  const size_t OFF_C = 17625600;      // h1 (4,915,200)  -> later v3
  const size_t OFF_D = 22540800;      // h2 (4,915,200); also c_buf early
  float* emb    = ws + OFF_A;
  float* gi     = ws + OFF_B;
  float* h1     = ws + OFF_C;
  float* h2     = ws + OFF_D;
  float* c_buf  = ws + OFF_D;         // dead before scan1 writes h2? no: used only pre-gemm0; h2 written at scan1
  float* out_ln = ws + OFF_A;
  float* v1     = ws + OFF_B;
  float* v2b    = ws + OFF_B + 4849664;
  float* qk3    = ws + OFF_B + 9568256;
  float* v3     = ws + OFF_C;

  // 1. token softmax
  softmax_c_kernel<<<(M_TOK*8 + 255)/256, 256, 0, stream>>>(code, x, c_buf);
  // 2. embedding
  embed_kernel<<<(M_TOK*E_SZ + 255)/256, 256, 0, stream>>>(c_buf, codebook, emb);
  // 3. gi layer0
  gemm_gi_kernel<<<dim3(12,300), 256, 0, stream>>>(emb, w_ih0, b_ih0, gi, E_SZ);
  // 4. scan layer0 -> h1 [b][t][dir*128+j]
  gru_scan_kernel<<<256, 384, 0, stream>>>(gi, w_hh0, b_hh0, h1, 256, 128);
  // 5. gi layer1
  gemm_gi_kernel<<<dim3(12,300), 256, 0, stream>>>(h1, w_ih1, b_ih1, gi, 256);
  // 6. scan layer1 -> h2 [dir][b][t][j]
  gru_scan_kernel<<<256, 384, 0, stream>>>(gi, w_hh1, b_hh1, h2, 128, M_TOK*HIDN);
  // 7. ln0 -> out_ln [b][n][t][16]
  ln0_kernel<<<(B_SZ*8*L_SZ + 255)/256, 256, 0, stream>>>(h2, ln0g, ln0b, out_ln);
  // 8. caps conv1: NC=8, HIN=150, HOUT=74, S=2
  caps_conv_kernel<<<dim3(19,B_SZ), 128, 0, stream>>>(out_ln, w1, ln1g, ln1b, v1, 8, 150, 74, 2, 1.f/32.f);
  // 9. caps conv2: NC=32, HIN=74, HOUT=72, S=1
  caps_conv_kernel<<<dim3(18,B_SZ), 128, 0, stream>>>(v1, w2, ln2g, ln2b, v2b, 32, 74, 72, 1, 1.f/32.f);
  // 10. v3
  v3pre_kernel<<<dim3(15,B_SZ), 256, 0, stream>>>(v2b, wfc, lnfg, lnfb, v3);
  // 11. routing softmax
  qk3_kernel<<<dim3(9,B_SZ), 256, 0, stream>>>(v2b, wfc, v3, qk3);
  // 12. nv3 + output
  nv3_out_kernel<<<dim3(15,B_SZ), 256, 0, stream>>>(v2b, wfc, qk3, lnfg, lnfb, out);
}

// Round 2
// 1255.564 us; speedup vs baseline: 1.2465x; 1.2465x over previous
//
#include <hip/hip_runtime.h>
#include <hip/hip_bf16.h>
#include <cstdint>

// Model constants
#define B_SZ 128
#define L_SZ 150
#define E_SZ 150
#define HIDN 128
#define M_TOK (B_SZ*L_SZ)   // 19200
#define G3 384              // 3*HID gates

typedef __attribute__((ext_vector_type(8))) short bf16x8;
typedef __attribute__((ext_vector_type(4))) float f32x4;

__device__ __forceinline__ float sigm(float x){ return 1.f/(1.f+__expf(-x)); }

__device__ __forceinline__ void storeval(float* p, float v){ *p = v; }
__device__ __forceinline__ void storeval(__hip_bfloat16* p, float v){ *p = __float2bfloat16(v); }

// ---------------- kernel 1: c[t][32] = softmax over last-4 of code[x[t]] ----------------
__global__ void softmax_c_kernel(const float* __restrict__ code, const int* __restrict__ x,
                                 float* __restrict__ c){
  int idx = blockIdx.x*blockDim.x + threadIdx.x;
  if (idx >= M_TOK*8) return;
  int t = idx >> 3, j = idx & 7;
  int tok = x[t];
  const float* p = code + ((size_t)tok*32 + j*4);
  float a0=p[0],a1=p[1],a2=p[2],a3=p[3];
  float mx = fmaxf(fmaxf(a0,a1),fmaxf(a2,a3));
  float e0=__expf(a0-mx),e1=__expf(a1-mx),e2=__expf(a2-mx),e3=__expf(a3-mx);
  float inv = 1.f/(e0+e1+e2+e3);
  float* q = c + ((size_t)t*32 + j*4);
  q[0]=e0*inv; q[1]=e1*inv; q[2]=e2*inv; q[3]=e3*inv;
}

// ---------------- kernel 2: emb bf16 padded: A0[t][e<160] = sum_i c[t][i]*cb[i][e] ----------------
__global__ void embed_bf16_kernel(const float* __restrict__ c, const float* __restrict__ cb,
                                  __hip_bfloat16* __restrict__ A0, int Kp){
  int idx = blockIdx.x*blockDim.x + threadIdx.x;
  if (idx >= M_TOK*160) return;
  int t = idx / 160; int e = idx - t*160;
  float acc = 0.f;
  if (e < E_SZ){
    const float* cr = c + (size_t)t*32;
    #pragma unroll
    for (int i=0;i<32;i++) acc += cr[i]*cb[i*E_SZ + e];
  }
  A0[(size_t)t*Kp + e] = __float2bfloat16(acc);
}

// ---------------- weight fp32->bf16 (K-padded) ----------------
__global__ void convW_kernel(const float* __restrict__ src, __hip_bfloat16* __restrict__ dst,
                             int N, int K, int Kp){
  int idx = blockIdx.x*blockDim.x + threadIdx.x;
  if (idx >= N*Kp) return;
  int n = idx / Kp; int k = idx - n*Kp;
  float v = (k < K) ? src[(size_t)n*K + k] : 0.f;
  dst[idx] = __float2bfloat16(v);
}

// ---------------- kernel 3: MFMA GEMM: out[dir][m][g] = A[m][Kp].W[n][Kp] + bias ----------------
// A bf16 [M][Kp], W bf16 [768][Kp], out fp32 gi layout [2][M_TOK][384]
__global__ __launch_bounds__(256) void gemm_mfma_kernel(
    const __hip_bfloat16* __restrict__ A, const __hip_bfloat16* __restrict__ W,
    const float* __restrict__ bias, float* __restrict__ out, int Kp)
{
  __shared__ __hip_bfloat16 As[128*32];
  __shared__ __hip_bfloat16 Bs[128*32];
  int tid = threadIdx.x;
  int m0 = blockIdx.y*128, n0 = blockIdx.x*128;
  int lane = tid & 63, wid = tid >> 6;
  int wr = wid >> 1, wc = wid & 1;
  int srow = tid >> 2, scol = (tid & 3) * 8;

  f32x4 acc[4][4];
  #pragma unroll
  for (int i=0;i<4;i++)
    #pragma unroll
    for (int j=0;j<4;j++) acc[i][j] = (f32x4){0.f,0.f,0.f,0.f};

  int r = lane & 15, kq = (lane >> 4) * 8;

  for (int k0 = 0; k0 < Kp; k0 += 32){
    __builtin_amdgcn_global_load_lds(
      (const __attribute__((address_space(1))) void*)(A + (size_t)(m0+srow)*Kp + k0 + scol),
      (__attribute__((address_space(3))) void*)(As + tid*8), 16, 0, 0);
    __builtin_amdgcn_global_load_lds(
      (const __attribute__((address_space(1))) void*)(A + (size_t)(m0+64+srow)*Kp + k0 + scol),
      (__attribute__((address_space(3))) void*)(As + 2048 + tid*8), 16, 0, 0);
    __builtin_amdgcn_global_load_lds(
      (const __attribute__((address_space(1))) void*)(W + (size_t)(n0+srow)*Kp + k0 + scol),
      (__attribute__((address_space(3))) void*)(Bs + tid*8), 16, 0, 0);
    __builtin_amdgcn_global_load_lds(
      (const __attribute__((address_space(1))) void*)(W + (size_t)(n0+64+srow)*Kp + k0 + scol),
      (__attribute__((address_space(3))) void*)(Bs + 2048 + tid*8), 16, 0, 0);
    __syncthreads();

    bf16x8 aF[4], bF[4];
    #pragma unroll
    for (int mi=0;mi<4;mi++) aF[mi] = *(const bf16x8*)(As + (wr*64 + mi*16 + r)*32 + kq);
    #pragma unroll
    for (int nj=0;nj<4;nj++) bF[nj] = *(const bf16x8*)(Bs + (wc*64 + nj*16 + r)*32 + kq);
    #pragma unroll
    for (int mi=0;mi<4;mi++)
      #pragma unroll
      for (int nj=0;nj<4;nj++)
        acc[mi][nj] = __builtin_amdgcn_mfma_f32_16x16x32_bf16(aF[mi], bF[nj], acc[mi][nj], 0, 0, 0);
    __syncthreads();
  }

  // epilogue: C[m][n], m=(lane>>4)*4+r2 within tile, n=lane&15
  #pragma unroll
  for (int nj=0;nj<4;nj++){
    int n = n0 + wc*64 + nj*16 + (lane & 15);
    int dir = (n >= G3) ? 1 : 0; int g = n - dir*G3;
    float bv = bias[n];
    #pragma unroll
    for (int mi=0;mi<4;mi++){
      #pragma unroll
      for (int r2=0;r2<4;r2++){
        int m = m0 + wr*64 + mi*16 + (lane>>4)*4 + r2;
        out[((size_t)dir*M_TOK + m)*G3 + g] = acc[mi][nj][r2] + bv;
      }
    }
  }
}

// ---------------- kernel 4: GRU scan. grid = 256 blocks (dir*128 + b), 384 threads ----------------
template <typename OT>
__global__ __launch_bounds__(384) void gru_scan_kernel(
    const float* __restrict__ gi,   // [2][19200][384] (m = b*150+t)
    const float* __restrict__ whh,  // [2][384][128]
    const float* __restrict__ bhh,  // [2][384]
    OT* __restrict__ out, int rowStride, size_t dirOffset)
{
  int bx = blockIdx.x; int dir = bx>>7; int b = bx&127;
  int tid = threadIdx.x;
  __shared__ float s_h[128];
  __shared__ float s_gh[384];
  float4 w[32];
  const float4* wrow = (const float4*)(whh + ((size_t)(dir*G3 + tid))*HIDN);
  #pragma unroll
  for (int i=0;i<32;i++) w[i] = wrow[i];
  float bias = bhh[dir*G3 + tid];
  if (tid < 128) s_h[tid] = 0.f;
  __syncthreads();
  const float* gib = gi + ((size_t)dir*M_TOK + (size_t)b*L_SZ)*G3;
  for (int s=0; s<L_SZ; ++s){
    int t = dir ? (L_SZ-1 - s) : s;
    // hoist gi loads (independent of matvec)
    float ir=0.f, iz=0.f, inn=0.f;
    if (tid < 128){
      const float* gr = gib + (size_t)t*G3;
      ir = gr[tid]; iz = gr[128+tid]; inn = gr[256+tid];
    }
    // matvec with 4 independent partial chains
    const float4* h4 = (const float4*)s_h;
    float p0=0.f,p1=0.f,p2=0.f,p3=bias;
    #pragma unroll
    for (int i=0;i<32;i+=4){
      float4 ha=h4[i], hb=h4[i+1], hc=h4[i+2], hd=h4[i+3];
      p0 += w[i].x*ha.x + w[i].y*ha.y + w[i].z*ha.z + w[i].w*ha.w;
      p1 += w[i+1].x*hb.x + w[i+1].y*hb.y + w[i+1].z*hb.z + w[i+1].w*hb.w;
      p2 += w[i+2].x*hc.x + w[i+2].y*hc.y + w[i+2].z*hc.z + w[i+2].w*hc.w;
      p3 += w[i+3].x*hd.x + w[i+3].y*hd.y + w[i+3].z*hd.z + w[i+3].w*hd.w;
    }
    s_gh[tid] = (p0+p1)+(p2+p3);
    __syncthreads();
    if (tid < 128){
      float hr = s_gh[tid], hz = s_gh[128+tid], hn = s_gh[256+tid];
      float rr = sigm(ir+hr);
      float zz = sigm(iz+hz);
      float xn = inn + rr*hn;
      float e2 = __expf(2.f*xn);
      float nn = 1.f - 2.f/(e2+1.f);   // tanh
      float hnew = (1.f-zz)*nn + zz*s_h[tid];
      s_h[tid] = hnew;
      storeval(&out[(size_t)(b*L_SZ + t)*rowStride + (size_t)dir*dirOffset + tid], hnew);
    }
    __syncthreads();
  }
}

// ---------------- kernel 5: out = fwd+bwd, reshape to [b][n=8][t][16], layernorm(16) ----------------
__global__ void ln0_kernel(const float* __restrict__ h2, const float* __restrict__ g,
                           const float* __restrict__ bt, float* __restrict__ out_ln){
  int idx = blockIdx.x*blockDim.x + threadIdx.x;
  if (idx >= B_SZ*8*L_SZ) return;
  int t = idx % L_SZ; int bn = idx / L_SZ; int n = bn & 7; int b = bn >> 3;
  const float* f0 = h2 + (size_t)(b*L_SZ+t)*HIDN + n*16;
  const float* f1 = f0 + (size_t)M_TOK*HIDN;
  float v[16]; float s = 0.f;
  #pragma unroll
  for (int d=0;d<16;d++){ v[d] = f0[d] + f1[d]; s += v[d]; }
  float mu = s*(1.f/16.f);
  float q = 0.f;
  #pragma unroll
  for (int d=0;d<16;d++){ float df = v[d]-mu; q += df*df; }
  float rs = rsqrtf(q*(1.f/16.f) + 1e-5f);
  float* o = out_ln + (size_t)idx*16;
  #pragma unroll
  for (int d=0;d<16;d++) o[d] = (v[d]-mu)*rs*g[d] + bt[d];
}

// ---------------- kernel 6: capsule conv (no-routing) + fused LN ----------------
__global__ __launch_bounds__(128) void caps_conv_kernel(
    const float* __restrict__ in, const float* __restrict__ w,
    const float* __restrict__ gam, const float* __restrict__ bet,
    float* __restrict__ out, int NC, int HIN, int HOUT, int S, float inv_m)
{
  __shared__ float wc[3*8*512];     // [k][nn][x][d][32] for 8-caps chunk
  __shared__ float in_s[8*9*16];
  int b = blockIdx.y;
  int h0 = blockIdx.x*4;
  int tid = threadIdx.x;
  int m = tid >> 2, d = tid & 3;
  int nrows = 3*S + 3;
  int row0 = h0 * S;
  int nch = NC >> 3;
  float acc[4][4] = {{0.f}};
  for (int ch=0; ch<nch; ++ch){
    int n0 = ch*8;
    for (int i=tid; i<3072; i+=128){
      int k = i/1024, off = i - k*1024;
      ((float4*)wc)[(size_t)k*1024 + off] = ((const float4*)w)[(size_t)(k*NC + n0)*128 + off];
    }
    int tot4 = 8*nrows*4;
    for (int i=tid;i<tot4;i+=128){
      int nn = i/(nrows*4); int rem = i - nn*nrows*4; int rr = rem>>2; int q = rem&3;
      int row = row0 + rr;
      float4 v = make_float4(0.f,0.f,0.f,0.f);
      if (row < HIN) v = ((const float4*)in)[((size_t)(b*NC + n0 + nn)*HIN + row)*4 + q];
      ((float4*)in_s)[(nn*nrows + rr)*4 + q] = v;
    }
    __syncthreads();
    #pragma unroll
    for (int k=0;k<3;k++)
    for (int nn=0;nn<8;nn++)
    #pragma unroll
    for (int xx=0;xx<4;xx++){
      float wv = wc[(((k*8+nn)*4+xx)*4 + d)*32 + m];
      #pragma unroll
      for (int hh=0;hh<4;hh++){
        const float* ip = &in_s[(nn*nrows + hh*S + k)*16 + xx];
        #pragma unroll
        for (int a=0;a<4;a++) acc[hh][a] += wv * ip[a*4];
      }
    }
    __syncthreads();
  }
  float gv[4], bv[4];
  #pragma unroll
  for (int a=0;a<4;a++){ gv[a]=gam[a*4+d]; bv[a]=bet[a*4+d]; }
  for (int hh=0; hh<4; ++hh){
    int h = h0+hh;
    if (h >= HOUT) break;       // uniform across block
    float s = 0.f;
    #pragma unroll
    for (int a=0;a<4;a++){ acc[hh][a] *= inv_m; s += acc[hh][a]; }
    s += __shfl_xor(s,1); s += __shfl_xor(s,2);
    float mu = s*(1.f/16.f);
    float q2 = 0.f;
    #pragma unroll
    for (int a=0;a<4;a++){ float df = acc[hh][a]-mu; q2 += df*df; }
    q2 += __shfl_xor(q2,1); q2 += __shfl_xor(q2,2);
    float rs = rsqrtf(q2*(1.f/16.f) + 1e-5f);
    float* op = out + ((size_t)(b*32+m)*HOUT + h)*16 + d;
    #pragma unroll
    for (int a=0;a<4;a++) op[a*4] = (acc[hh][a]-mu)*rs*gv[a] + bv[a];
  }
}

// ---------------- kernel 7: v3[b][m][16] = LN( (1/15) sum_{n,x} fi*wfc ) ----------------
__global__ __launch_bounds__(256) void v3pre_kernel(
    const float* __restrict__ v2, const float* __restrict__ wfc,
    const float* __restrict__ g, const float* __restrict__ bt, float* __restrict__ v3)
{
  int m = blockIdx.x; int b = blockIdx.y; int tid = threadIdx.x;
  float acc[16];
  #pragma unroll
  for (int i=0;i<16;i++) acc[i]=0.f;
  for (int n = tid; n < 2304; n += 256){
    const float4* fp = (const float4*)(v2 + (size_t)(b*2304 + n)*16);
    float4 f0=fp[0],f1=fp[1],f2=fp[2],f3=fp[3];
    float f[16]={f0.x,f0.y,f0.z,f0.w,f1.x,f1.y,f1.z,f1.w,f2.x,f2.y,f2.z,f2.w,f3.x,f3.y,f3.z,f3.w};
    float wv[16];
    #pragma unroll
    for (int x=0;x<4;x++)
      #pragma unroll
      for (int d=0;d<4;d++) wv[x*4+d] = wfc[(size_t)((n*4+x)*4+d)*15 + m];
    #pragma unroll
    for (int a=0;a<4;a++)
      #pragma unroll
      for (int x=0;x<4;x++){
        float fv = f[a*4+x];
        #pragma unroll
        for (int d=0;d<4;d++) acc[a*4+d] += fv*wv[x*4+d];
      }
  }
  __shared__ float red[4][16];
  int lane = tid&63, wv_ = tid>>6;
  #pragma unroll
  for (int i=0;i<16;i++){
    float v = acc[i];
    v += __shfl_xor(v,1); v += __shfl_xor(v,2); v += __shfl_xor(v,4);
    v += __shfl_xor(v,8); v += __shfl_xor(v,16); v += __shfl_xor(v,32);
    if (lane==0) red[wv_][i] = v;
  }
  __syncthreads();
  if (tid < 16){
    float s = (red[0][tid]+red[1][tid]+red[2][tid]+red[3][tid]) * (1.f/15.f);
    float tot = s; tot += __shfl_xor(tot,1); tot += __shfl_xor(tot,2);
    tot += __shfl_xor(tot,4); tot += __shfl_xor(tot,8);
    float mu = tot*(1.f/16.f);
    float df = s-mu;
    float q = df*df; q += __shfl_xor(q,1); q += __shfl_xor(q,2);
    q += __shfl_xor(q,4); q += __shfl_xor(q,8);
    float rs = rsqrtf(q*(1.f/16.f) + 1e-5f);
    v3[(size_t)(b*15+m)*16 + tid] = df*rs*g[tid] + bt[tid];
  }
}

// ---------------- kernel 8: routing logits -> qk3[b][n][15] ----------------
__global__ __launch_bounds__(256) void qk3_kernel(
    const float* __restrict__ v2, const float* __restrict__ wfc,
    const float* __restrict__ v3, float* __restrict__ qk3)
{
  int b = blockIdx.y; int tid = threadIdx.x;
  int n = blockIdx.x*256 + tid;
  __shared__ float v3s[240];
  if (tid < 240) v3s[tid] = v3[(size_t)b*240 + tid];
  __syncthreads();
  const float4* fp = (const float4*)(v2 + (size_t)(b*2304 + n)*16);
  float4 f0=fp[0],f1=fp[1],f2=fp[2],f3=fp[3];
  float f[16]={f0.x,f0.y,f0.z,f0.w,f1.x,f1.y,f1.z,f1.w,f2.x,f2.y,f2.z,f2.w,f3.x,f3.y,f3.z,f3.w};
  float lg[15];
  for (int m=0;m<15;m++){
    float s = 0.f;
    #pragma unroll
    for (int x=0;x<4;x++)
      #pragma unroll
      for (int d=0;d<4;d++){
        float wv = wfc[(size_t)((n*4+x)*4+d)*15 + m];
        float p = f[x]*v3s[m*16+d] + f[4+x]*v3s[m*16+4+d]
                + f[8+x]*v3s[m*16+8+d] + f[12+x]*v3s[m*16+12+d];
        s += wv*p;
      }
    lg[m] = s*0.25f;
  }
  float mx = lg[0];
  for (int m=1;m<15;m++) mx = fmaxf(mx, lg[m]);
  float se = 0.f;
  for (int m=0;m<15;m++){ lg[m] = __expf(lg[m]-mx); se += lg[m]; }
  float inv = 1.f/se;
  float s2 = 0.f;
  for (int m=0;m<15;m++){ lg[m] *= inv; s2 += lg[m]; }
  float inv2 = 1.f/(s2 + 1e-10f);
  float* qp = qk3 + (size_t)(b*2304 + n)*15;
  for (int m=0;m<15;m++) qp[m] = lg[m]*inv2;
}

// ---------------- kernel 9: nv3 = sum_n qk*fi*wfc ; LN ; out = nrm^2/(1+nrm^2) ----------------
__global__ __launch_bounds__(256) void nv3_out_kernel(
    const float* __restrict__ v2, const float* __restrict__ wfc,
    const float* __restrict__ qk3, const float* __restrict__ g,
    const float* __restrict__ bt, float* __restrict__ out)
{
  int m = blockIdx.x; int b = blockIdx.y; int tid = threadIdx.x;
  float acc[16];
  #pragma unroll
  for (int i=0;i<16;i++) acc[i]=0.f;
  for (int n = tid; n < 2304; n += 256){
    float q = qk3[(size_t)(b*2304+n)*15 + m];
    const float4* fp = (const float4*)(v2 + (size_t)(b*2304 + n)*16);
    float4 f0=fp[0],f1=fp[1],f2=fp[2],f3=fp[3];
    float f[16]={f0.x,f0.y,f0.z,f0.w,f1.x,f1.y,f1.z,f1.w,f2.x,f2.y,f2.z,f2.w,f3.x,f3.y,f3.z,f3.w};
    float wv[16];
    #pragma unroll
    for (int x=0;x<4;x++)
      #pragma unroll
      for (int d=0;d<4;d++) wv[x*4+d] = wfc[(size_t)((n*4+x)*4+d)*15 + m];
    #pragma unroll
    for (int a=0;a<4;a++)
      #pragma unroll
      for (int d=0;d<4;d++){
        float u = f[a*4+0]*wv[0*4+d] + f[a*4+1]*wv[1*4+d] + f[a*4+2]*wv[2*4+d] + f[a*4+3]*wv[3*4+d];
        acc[a*4+d] += q*u;
      }
  }
  __shared__ float red[4][16];
  int lane = tid&63, wv_ = tid>>6;
  #pragma unroll
  for (int i=0;i<16;i++){
    float v = acc[i];
    v += __shfl_xor(v,1); v += __shfl_xor(v,2); v += __shfl_xor(v,4);
    v += __shfl_xor(v,8); v += __shfl_xor(v,16); v += __shfl_xor(v,32);
    if (lane==0) red[wv_][i] = v;
  }
  __syncthreads();
  if (tid < 16){
    float s = red[0][tid]+red[1][tid]+red[2][tid]+red[3][tid];
    float tot = s; tot += __shfl_xor(tot,1); tot += __shfl_xor(tot,2);
    tot += __shfl_xor(tot,4); tot += __shfl_xor(tot,8);
    float mu = tot*(1.f/16.f);
    float df = s-mu;
    float q = df*df; q += __shfl_xor(q,1); q += __shfl_xor(q,2);
    q += __shfl_xor(q,4); q += __shfl_xor(q,8);
    float rs = rsqrtf(q*(1.f/16.f) + 1e-5f);
    float v = df*rs*g[tid] + bt[tid];
    float q2 = v*v; q2 += __shfl_xor(q2,1); q2 += __shfl_xor(q2,2);
    q2 += __shfl_xor(q2,4); q2 += __shfl_xor(q2,8);
    if (tid==0) out[(size_t)b*15 + m] = q2/(1.f+q2);
  }
}

// =================================================================================
extern "C" void kernel_launch(void* const* d_in, const int* in_sizes, int n_in,
                              void* d_out, int out_size, void* d_ws, size_t ws_size,
                              hipStream_t stream) {
  const float* code     = (const float*)d_in[0];
  const float* codebook = (const float*)d_in[1];
  const float* w_ih0    = (const float*)d_in[2];
  const float* w_hh0    = (const float*)d_in[3];
  const float* b_ih0    = (const float*)d_in[4];
  const float* b_hh0    = (const float*)d_in[5];
  const float* w_ih1    = (const float*)d_in[6];
  const float* w_hh1    = (const float*)d_in[7];
  const float* b_ih1    = (const float*)d_in[8];
  const float* b_hh1    = (const float*)d_in[9];
  const float* ln0g     = (const float*)d_in[10];
  const float* ln0b     = (const float*)d_in[11];
  const float* w1       = (const float*)d_in[12];
  const float* ln1g     = (const float*)d_in[13];
  const float* ln1b     = (const float*)d_in[14];
  const float* w2       = (const float*)d_in[15];
  const float* ln2g     = (const float*)d_in[16];
  const float* ln2b     = (const float*)d_in[17];
  const float* wfc      = (const float*)d_in[18];
  const float* lnfg     = (const float*)d_in[19];
  const float* lnfb     = (const float*)d_in[20];
  const int*   x        = (const int*)d_in[21];
  float* out = (float*)d_out;
  float* ws  = (float*)d_ws;

  // workspace layout (float offsets); total 24,766,464 f = 99.1 MB
  float* gi   = ws + 0;                              // 14,745,600 f  [gemm->scan, per layer]
  float* v1   = ws + 0;                              //  4,849,664 f  (after scans done)
  float* v2b  = ws + 4849664;                        //  4,718,592 f
  float* qk3  = ws + 9568256;                        //  4,423,680 f
  __hip_bfloat16* h1b = (__hip_bfloat16*)(ws + 14745600);  // 19200x256 bf16
  float* h2   = ws + 17203200;                       //  4,915,200 f
  float* c_buf= ws + 17203200;                       // aliases h2 (dead before scan1)
  float* out_ln = ws + 22118400;                     //  2,457,600 f
  __hip_bfloat16* A0b = (__hip_bfloat16*)(ws + 22118400);  // aliases out_ln (dead before ln0)
  __hip_bfloat16* W0b = (__hip_bfloat16*)(ws + 24576000);  // 768x160 bf16
  __hip_bfloat16* W1b = (__hip_bfloat16*)(ws + 24637440);  // 768x256 bf16
  float* v3   = ws + 24735744;                       //     30,720 f

  // 1. token softmax
  softmax_c_kernel<<<(M_TOK*8 + 255)/256, 256, 0, stream>>>(code, x, c_buf);
  // 2. embedding -> bf16 padded [19200][160]
  embed_bf16_kernel<<<(M_TOK*160 + 255)/256, 256, 0, stream>>>(c_buf, codebook, A0b, 160);
  // 2b. weight conversions
  convW_kernel<<<(768*160 + 255)/256, 256, 0, stream>>>(w_ih0, W0b, 768, 150, 160);
  convW_kernel<<<(768*256 + 255)/256, 256, 0, stream>>>(w_ih1, W1b, 768, 256, 256);
  // 3. gi layer0 (MFMA)
  gemm_mfma_kernel<<<dim3(6,150), 256, 0, stream>>>(A0b, W0b, b_ih0, gi, 160);
  // 4. scan layer0 -> h1 bf16 [b][t][dir*128+j]
  gru_scan_kernel<__hip_bfloat16><<<256, 384, 0, stream>>>(gi, w_hh0, b_hh0, h1b, 256, (size_t)128);
  // 5. gi layer1 (MFMA)
  gemm_mfma_kernel<<<dim3(6,150), 256, 0, stream>>>(h1b, W1b, b_ih1, gi, 256);
  // 6. scan layer1 -> h2 fp32 [dir][b][t][j]
  gru_scan_kernel<float><<<256, 384, 0, stream>>>(gi, w_hh1, b_hh1, h2, 128, (size_t)M_TOK*HIDN);
  // 7. ln0 -> out_ln [b][n][t][16]
  ln0_kernel<<<(B_SZ*8*L_SZ + 255)/256, 256, 0, stream>>>(h2, ln0g, ln0b, out_ln);
  // 8. caps conv1: NC=8, HIN=150, HOUT=74, S=2
  caps_conv_kernel<<<dim3(19,B_SZ), 128, 0, stream>>>(out_ln, w1, ln1g, ln1b, v1, 8, 150, 74, 2, 1.f/32.f);
  // 9. caps conv2: NC=32, HIN=74, HOUT=72, S=1
  caps_conv_kernel<<<dim3(18,B_SZ), 128, 0, stream>>>(v1, w2, ln2g, ln2b, v2b, 32, 74, 72, 1, 1.f/32.f);
  // 10. v3
  v3pre_kernel<<<dim3(15,B_SZ), 256, 0, stream>>>(v2b, wfc, lnfg, lnfb, v3);
  // 11. routing softmax
  qk3_kernel<<<dim3(9,B_SZ), 256, 0, stream>>>(v2b, wfc, v3, qk3);
  // 12. nv3 + output
  nv3_out_kernel<<<dim3(15,B_SZ), 256, 0, stream>>>(v2b, wfc, qk3, lnfg, lnfb, out);
}

// Round 3
// 841.870 us; speedup vs baseline: 1.8590x; 1.4914x over previous
//
#include <hip/hip_runtime.h>
#include <hip/hip_bf16.h>
#include <cstdint>

// Model constants
#define B_SZ 128
#define L_SZ 150
#define E_SZ 150
#define HIDN 128
#define M_TOK (B_SZ*L_SZ)   // 19200
#define G3 384              // 3*HID gates
#define NFC 2304            // capsule-FC input count
#define NCH 72              // n-chunks per b (32 n each)

typedef __attribute__((ext_vector_type(8))) short bf16x8;
typedef __attribute__((ext_vector_type(4))) float f32x4;

__device__ __forceinline__ float sigm(float x){ return 1.f/(1.f+__expf(-x)); }

__device__ __forceinline__ void storeval(float* p, float v){ *p = v; }
__device__ __forceinline__ void storeval(__hip_bfloat16* p, float v){ *p = __float2bfloat16(v); }

// ---------------- kernel 1: c[t][32] = softmax over last-4 of code[x[t]] ----------------
__global__ void softmax_c_kernel(const float* __restrict__ code, const int* __restrict__ x,
                                 float* __restrict__ c){
  int idx = blockIdx.x*blockDim.x + threadIdx.x;
  if (idx >= M_TOK*8) return;
  int t = idx >> 3, j = idx & 7;
  int tok = x[t];
  const float* p = code + ((size_t)tok*32 + j*4);
  float a0=p[0],a1=p[1],a2=p[2],a3=p[3];
  float mx = fmaxf(fmaxf(a0,a1),fmaxf(a2,a3));
  float e0=__expf(a0-mx),e1=__expf(a1-mx),e2=__expf(a2-mx),e3=__expf(a3-mx);
  float inv = 1.f/(e0+e1+e2+e3);
  float* q = c + ((size_t)t*32 + j*4);
  q[0]=e0*inv; q[1]=e1*inv; q[2]=e2*inv; q[3]=e3*inv;
}

// ---------------- kernel 2: emb bf16 padded ----------------
__global__ void embed_bf16_kernel(const float* __restrict__ c, const float* __restrict__ cb,
                                  __hip_bfloat16* __restrict__ A0, int Kp){
  int idx = blockIdx.x*blockDim.x + threadIdx.x;
  if (idx >= M_TOK*160) return;
  int t = idx / 160; int e = idx - t*160;
  float acc = 0.f;
  if (e < E_SZ){
    const float* cr = c + (size_t)t*32;
    #pragma unroll
    for (int i=0;i<32;i++) acc += cr[i]*cb[i*E_SZ + e];
  }
  A0[(size_t)t*Kp + e] = __float2bfloat16(acc);
}

// ---------------- weight fp32->bf16 (K-padded) ----------------
__global__ void convW_kernel(const float* __restrict__ src, __hip_bfloat16* __restrict__ dst,
                             int N, int K, int Kp){
  int idx = blockIdx.x*blockDim.x + threadIdx.x;
  if (idx >= N*Kp) return;
  int n = idx / Kp; int k = idx - n*Kp;
  float v = (k < K) ? src[(size_t)n*K + k] : 0.f;
  dst[idx] = __float2bfloat16(v);
}

// ---------------- kernel 3: MFMA GEMM ----------------
__global__ __launch_bounds__(256) void gemm_mfma_kernel(
    const __hip_bfloat16* __restrict__ A, const __hip_bfloat16* __restrict__ W,
    const float* __restrict__ bias, float* __restrict__ out, int Kp)
{
  __shared__ __hip_bfloat16 As[128*32];
  __shared__ __hip_bfloat16 Bs[128*32];
  int tid = threadIdx.x;
  int m0 = blockIdx.y*128, n0 = blockIdx.x*128;
  int lane = tid & 63, wid = tid >> 6;
  int wr = wid >> 1, wc = wid & 1;
  int srow = tid >> 2, scol = (tid & 3) * 8;

  f32x4 acc[4][4];
  #pragma unroll
  for (int i=0;i<4;i++)
    #pragma unroll
    for (int j=0;j<4;j++) acc[i][j] = (f32x4){0.f,0.f,0.f,0.f};

  int r = lane & 15, kq = (lane >> 4) * 8;

  for (int k0 = 0; k0 < Kp; k0 += 32){
    __builtin_amdgcn_global_load_lds(
      (const __attribute__((address_space(1))) void*)(A + (size_t)(m0+srow)*Kp + k0 + scol),
      (__attribute__((address_space(3))) void*)(As + tid*8), 16, 0, 0);
    __builtin_amdgcn_global_load_lds(
      (const __attribute__((address_space(1))) void*)(A + (size_t)(m0+64+srow)*Kp + k0 + scol),
      (__attribute__((address_space(3))) void*)(As + 2048 + tid*8), 16, 0, 0);
    __builtin_amdgcn_global_load_lds(
      (const __attribute__((address_space(1))) void*)(W + (size_t)(n0+srow)*Kp + k0 + scol),
      (__attribute__((address_space(3))) void*)(Bs + tid*8), 16, 0, 0);
    __builtin_amdgcn_global_load_lds(
      (const __attribute__((address_space(1))) void*)(W + (size_t)(n0+64+srow)*Kp + k0 + scol),
      (__attribute__((address_space(3))) void*)(Bs + 2048 + tid*8), 16, 0, 0);
    __syncthreads();

    bf16x8 aF[4], bF[4];
    #pragma unroll
    for (int mi=0;mi<4;mi++) aF[mi] = *(const bf16x8*)(As + (wr*64 + mi*16 + r)*32 + kq);
    #pragma unroll
    for (int nj=0;nj<4;nj++) bF[nj] = *(const bf16x8*)(Bs + (wc*64 + nj*16 + r)*32 + kq);
    #pragma unroll
    for (int mi=0;mi<4;mi++)
      #pragma unroll
      for (int nj=0;nj<4;nj++)
        acc[mi][nj] = __builtin_amdgcn_mfma_f32_16x16x32_bf16(aF[mi], bF[nj], acc[mi][nj], 0, 0, 0);
    __syncthreads();
  }

  #pragma unroll
  for (int nj=0;nj<4;nj++){
    int n = n0 + wc*64 + nj*16 + (lane & 15);
    int dir = (n >= G3) ? 1 : 0; int g = n - dir*G3;
    float bv = bias[n];
    #pragma unroll
    for (int mi=0;mi<4;mi++){
      #pragma unroll
      for (int r2=0;r2<4;r2++){
        int m = m0 + wr*64 + mi*16 + (lane>>4)*4 + r2;
        out[((size_t)dir*M_TOK + m)*G3 + g] = acc[mi][nj][r2] + bv;
      }
    }
  }
}

// ---------------- kernel 4: GRU scan ----------------
template <typename OT>
__global__ __launch_bounds__(384) void gru_scan_kernel(
    const float* __restrict__ gi, const float* __restrict__ whh,
    const float* __restrict__ bhh, OT* __restrict__ out, int rowStride, size_t dirOffset)
{
  int bx = blockIdx.x; int dir = bx>>7; int b = bx&127;
  int tid = threadIdx.x;
  __shared__ float s_h[128];
  __shared__ float s_gh[384];
  float4 w[32];
  const float4* wrow = (const float4*)(whh + ((size_t)(dir*G3 + tid))*HIDN);
  #pragma unroll
  for (int i=0;i<32;i++) w[i] = wrow[i];
  float bias = bhh[dir*G3 + tid];
  if (tid < 128) s_h[tid] = 0.f;
  __syncthreads();
  const float* gib = gi + ((size_t)dir*M_TOK + (size_t)b*L_SZ)*G3;
  for (int s=0; s<L_SZ; ++s){
    int t = dir ? (L_SZ-1 - s) : s;
    float ir=0.f, iz=0.f, inn=0.f;
    if (tid < 128){
      const float* gr = gib + (size_t)t*G3;
      ir = gr[tid]; iz = gr[128+tid]; inn = gr[256+tid];
    }
    const float4* h4 = (const float4*)s_h;
    float p0=0.f,p1=0.f,p2=0.f,p3=bias;
    #pragma unroll
    for (int i=0;i<32;i+=4){
      float4 ha=h4[i], hb=h4[i+1], hc=h4[i+2], hd=h4[i+3];
      p0 += w[i].x*ha.x + w[i].y*ha.y + w[i].z*ha.z + w[i].w*ha.w;
      p1 += w[i+1].x*hb.x + w[i+1].y*hb.y + w[i+1].z*hb.z + w[i+1].w*hb.w;
      p2 += w[i+2].x*hc.x + w[i+2].y*hc.y + w[i+2].z*hc.z + w[i+2].w*hc.w;
      p3 += w[i+3].x*hd.x + w[i+3].y*hd.y + w[i+3].z*hd.z + w[i+3].w*hd.w;
    }
    s_gh[tid] = (p0+p1)+(p2+p3);
    __syncthreads();
    if (tid < 128){
      float hr = s_gh[tid], hz = s_gh[128+tid], hn = s_gh[256+tid];
      float rr = sigm(ir+hr);
      float zz = sigm(iz+hz);
      float xn = inn + rr*hn;
      float e2 = __expf(2.f*xn);
      float nn = 1.f - 2.f/(e2+1.f);
      float hnew = (1.f-zz)*nn + zz*s_h[tid];
      s_h[tid] = hnew;
      storeval(&out[(size_t)(b*L_SZ + t)*rowStride + (size_t)dir*dirOffset + tid], hnew);
    }
    __syncthreads();
  }
}

// ---------------- kernel 5: ln0 ----------------
__global__ void ln0_kernel(const float* __restrict__ h2, const float* __restrict__ g,
                           const float* __restrict__ bt, float* __restrict__ out_ln){
  int idx = blockIdx.x*blockDim.x + threadIdx.x;
  if (idx >= B_SZ*8*L_SZ) return;
  int t = idx % L_SZ; int bn = idx / L_SZ; int n = bn & 7; int b = bn >> 3;
  const float* f0 = h2 + (size_t)(b*L_SZ+t)*HIDN + n*16;
  const float* f1 = f0 + (size_t)M_TOK*HIDN;
  float v[16]; float s = 0.f;
  #pragma unroll
  for (int d=0;d<16;d++){ v[d] = f0[d] + f1[d]; s += v[d]; }
  float mu = s*(1.f/16.f);
  float q = 0.f;
  #pragma unroll
  for (int d=0;d<16;d++){ float df = v[d]-mu; q += df*df; }
  float rs = rsqrtf(q*(1.f/16.f) + 1e-5f);
  float* o = out_ln + (size_t)idx*16;
  #pragma unroll
  for (int d=0;d<16;d++) o[d] = (v[d]-mu)*rs*g[d] + bt[d];
}

// ---------------- kernel 6: capsule conv (no-routing) + fused LN ----------------
__global__ __launch_bounds__(128) void caps_conv_kernel(
    const float* __restrict__ in, const float* __restrict__ w,
    const float* __restrict__ gam, const float* __restrict__ bet,
    float* __restrict__ out, int NC, int HIN, int HOUT, int S, float inv_m)
{
  __shared__ float wc[3*8*512];
  __shared__ float in_s[8*9*16];
  int b = blockIdx.y;
  int h0 = blockIdx.x*4;
  int tid = threadIdx.x;
  int m = tid >> 2, d = tid & 3;
  int nrows = 3*S + 3;
  int row0 = h0 * S;
  int nch = NC >> 3;
  float acc[4][4] = {{0.f}};
  for (int ch=0; ch<nch; ++ch){
    int n0 = ch*8;
    for (int i=tid; i<3072; i+=128){
      int k = i/1024, off = i - k*1024;
      ((float4*)wc)[(size_t)k*1024 + off] = ((const float4*)w)[(size_t)(k*NC + n0)*128 + off];
    }
    int tot4 = 8*nrows*4;
    for (int i=tid;i<tot4;i+=128){
      int nn = i/(nrows*4); int rem = i - nn*nrows*4; int rr = rem>>2; int q = rem&3;
      int row = row0 + rr;
      float4 v = make_float4(0.f,0.f,0.f,0.f);
      if (row < HIN) v = ((const float4*)in)[((size_t)(b*NC + n0 + nn)*HIN + row)*4 + q];
      ((float4*)in_s)[(nn*nrows + rr)*4 + q] = v;
    }
    __syncthreads();
    #pragma unroll
    for (int k=0;k<3;k++)
    for (int nn=0;nn<8;nn++)
    #pragma unroll
    for (int xx=0;xx<4;xx++){
      float wv = wc[(((k*8+nn)*4+xx)*4 + d)*32 + m];
      #pragma unroll
      for (int hh=0;hh<4;hh++){
        const float* ip = &in_s[(nn*nrows + hh*S + k)*16 + xx];
        #pragma unroll
        for (int a=0;a<4;a++) acc[hh][a] += wv * ip[a*4];
      }
    }
    __syncthreads();
  }
  float gv[4], bv[4];
  #pragma unroll
  for (int a=0;a<4;a++){ gv[a]=gam[a*4+d]; bv[a]=bet[a*4+d]; }
  for (int hh=0; hh<4; ++hh){
    int h = h0+hh;
    if (h >= HOUT) break;
    float s = 0.f;
    #pragma unroll
    for (int a=0;a<4;a++){ acc[hh][a] *= inv_m; s += acc[hh][a]; }
    s += __shfl_xor(s,1); s += __shfl_xor(s,2);
    float mu = s*(1.f/16.f);
    float q2 = 0.f;
    #pragma unroll
    for (int a=0;a<4;a++){ float df = acc[hh][a]-mu; q2 += df*df; }
    q2 += __shfl_xor(q2,1); q2 += __shfl_xor(q2,2);
    float rs = rsqrtf(q2*(1.f/16.f) + 1e-5f);
    float* op = out + ((size_t)(b*32+m)*HOUT + h)*16 + d;
    #pragma unroll
    for (int a=0;a<4;a++) op[a*4] = (acc[hh][a]-mu)*rs*gv[a] + bv[a];
  }
}

// ---------------- kernel 7: transpose wfc -> wT[n][m][d][x] ----------------
__global__ void transposeW_kernel(const float* __restrict__ wfc, float* __restrict__ wT){
  int idx = blockIdx.x*blockDim.x + threadIdx.x;
  if (idx >= NFC*240) return;
  int n = idx / 240; int r = idx - n*240;
  int m = r >> 4; int dd = (r >> 2) & 3; int xx = r & 3;
  wT[idx] = wfc[(size_t)((n*4+xx)*4+dd)*15 + m];
}

// ---------------- kernel 8: routing pass (templated: uniform vs softmax) ----------------
// grid (NCH, B). 256 threads = 16 nloc x 16 ad; each thread handles 2 n's.
// part[b][ch][240] partial nv sums (deterministic reduce later).
template<int WITH_SM>
__global__ __launch_bounds__(256) void route_pass_kernel(
    const float* __restrict__ v2,    // [B][2304][16]  (n, a*4+x)
    const float* __restrict__ wT,    // [2304][15][4][4] (n, m, d, x)
    const float* __restrict__ v3,    // [B][15][16]    (m, a*4+d)  (only WITH_SM)
    float* __restrict__ part)        // [B][NCH][240]
{
  int ch = blockIdx.x, b = blockIdx.y;
  int tid = threadIdx.x;
  int nloc = tid >> 4;
  int ad = tid & 15; int a = ad >> 2; int d = ad & 3;
  int n0 = ch*32;

  __shared__ float wTs[32*240];   // 30 KB
  __shared__ float fis[32*16];    // 2 KB
  __shared__ float v3s[240];
  __shared__ float accs[3840];    // [240][16 nloc]

  for (int i=tid; i<1920; i+=256)
    ((float4*)wTs)[i] = ((const float4*)(wT + (size_t)n0*240))[i];
  for (int i=tid; i<128; i+=256)
    ((float4*)fis)[i] = ((const float4*)(v2 + ((size_t)b*NFC + n0)*16))[i];
  if (WITH_SM && tid < 240) v3s[tid] = v3[(size_t)b*240 + tid];
  __syncthreads();

  float acc[15];
  #pragma unroll
  for (int m=0;m<15;m++) acc[m]=0.f;

  #pragma unroll
  for (int i=0;i<2;i++){
    int nl = nloc*2 + i;
    float4 fv = *(const float4*)&fis[nl*16 + a*4];
    float votes[15], lg[15];
    #pragma unroll
    for (int m=0;m<15;m++){
      float4 wv = *(const float4*)&wTs[nl*240 + m*16 + d*4];
      float vt = fv.x*wv.x + fv.y*wv.y + fv.z*wv.z + fv.w*wv.w;
      votes[m] = vt;
      if (WITH_SM){
        float p = vt * v3s[m*16 + ad];
        p += __shfl_xor(p,1); p += __shfl_xor(p,2);
        p += __shfl_xor(p,4); p += __shfl_xor(p,8);
        lg[m] = p * 0.25f;   // SCALE = 1/sqrt(16)
      }
    }
    if (WITH_SM){
      float mx = lg[0];
      #pragma unroll
      for (int m=1;m<15;m++) mx = fmaxf(mx, lg[m]);
      float se = 0.f;
      #pragma unroll
      for (int m=0;m<15;m++){ lg[m] = __expf(lg[m]-mx); se += lg[m]; }
      float inv = 1.f/se;
      float s2 = 0.f;
      #pragma unroll
      for (int m=0;m<15;m++){ lg[m] *= inv; s2 += lg[m]; }
      float inv2 = 1.f/(s2 + 1e-10f);
      #pragma unroll
      for (int m=0;m<15;m++) acc[m] += lg[m]*inv2*votes[m];
    } else {
      #pragma unroll
      for (int m=0;m<15;m++) acc[m] += votes[m]*(1.f/15.f);
    }
  }
  #pragma unroll
  for (int m=0;m<15;m++) accs[(m*16+ad)*16 + nloc] = acc[m];
  __syncthreads();
  if (tid < 240){
    float s = 0.f;
    #pragma unroll
    for (int k=0;k<16;k++) s += accs[tid*16 + k];
    part[((size_t)b*NCH + ch)*240 + tid] = s;
  }
}

// ---------------- kernel 9: reduce partials -> LN -> v3 ----------------
__global__ __launch_bounds__(240) void reduce_v3_kernel(
    const float* __restrict__ part, const float* __restrict__ g,
    const float* __restrict__ bt, float* __restrict__ v3)
{
  int b = blockIdx.x; int tid = threadIdx.x;   // 240 threads, groups of 16 per m
  int ad = tid & 15;
  float s = 0.f;
  for (int ch=0; ch<NCH; ++ch) s += part[((size_t)b*NCH + ch)*240 + tid];
  float tot = s;
  tot += __shfl_xor(tot,1); tot += __shfl_xor(tot,2);
  tot += __shfl_xor(tot,4); tot += __shfl_xor(tot,8);
  float mu = tot*(1.f/16.f);
  float df = s - mu;
  float q = df*df;
  q += __shfl_xor(q,1); q += __shfl_xor(q,2);
  q += __shfl_xor(q,4); q += __shfl_xor(q,8);
  float rs = rsqrtf(q*(1.f/16.f) + 1e-5f);
  v3[(size_t)b*240 + tid] = df*rs*g[ad] + bt[ad];
}

// ---------------- kernel 10: reduce partials -> LN -> norm head -> out ----------------
__global__ __launch_bounds__(240) void reduce_out_kernel(
    const float* __restrict__ part, const float* __restrict__ g,
    const float* __restrict__ bt, float* __restrict__ out)
{
  int b = blockIdx.x; int tid = threadIdx.x;
  int m = tid >> 4; int ad = tid & 15;
  float s = 0.f;
  for (int ch=0; ch<NCH; ++ch) s += part[((size_t)b*NCH + ch)*240 + tid];
  float tot = s;
  tot += __shfl_xor(tot,1); tot += __shfl_xor(tot,2);
  tot += __shfl_xor(tot,4); tot += __shfl_xor(tot,8);
  float mu = tot*(1.f/16.f);
  float df = s - mu;
  float q = df*df;
  q += __shfl_xor(q,1); q += __shfl_xor(q,2);
  q += __shfl_xor(q,4); q += __shfl_xor(q,8);
  float rs = rsqrtf(q*(1.f/16.f) + 1e-5f);
  float v = df*rs*g[ad] + bt[ad];
  float q2 = v*v;
  q2 += __shfl_xor(q2,1); q2 += __shfl_xor(q2,2);
  q2 += __shfl_xor(q2,4); q2 += __shfl_xor(q2,8);
  if (ad == 0) out[(size_t)b*15 + m] = q2/(1.f+q2);
}

// =================================================================================
extern "C" void kernel_launch(void* const* d_in, const int* in_sizes, int n_in,
                              void* d_out, int out_size, void* d_ws, size_t ws_size,
                              hipStream_t stream) {
  const float* code     = (const float*)d_in[0];
  const float* codebook = (const float*)d_in[1];
  const float* w_ih0    = (const float*)d_in[2];
  const float* w_hh0    = (const float*)d_in[3];
  const float* b_ih0    = (const float*)d_in[4];
  const float* b_hh0    = (const float*)d_in[5];
  const float* w_ih1    = (const float*)d_in[6];
  const float* w_hh1    = (const float*)d_in[7];
  const float* b_ih1    = (const float*)d_in[8];
  const float* b_hh1    = (const float*)d_in[9];
  const float* ln0g     = (const float*)d_in[10];
  const float* ln0b     = (const float*)d_in[11];
  const float* w1       = (const float*)d_in[12];
  const float* ln1g     = (const float*)d_in[13];
  const float* ln1b     = (const float*)d_in[14];
  const float* w2       = (const float*)d_in[15];
  const float* ln2g     = (const float*)d_in[16];
  const float* ln2b     = (const float*)d_in[17];
  const float* wfc      = (const float*)d_in[18];
  const float* lnfg     = (const float*)d_in[19];
  const float* lnfb     = (const float*)d_in[20];
  const int*   x        = (const int*)d_in[21];
  float* out = (float*)d_out;
  float* ws  = (float*)d_ws;

  // workspace layout (float offsets); high-water ~24.77M floats (99 MB)
  float* gi   = ws + 0;                              // 14,745,600 f (dead after scan2)
  float* v1   = ws + 0;                              //  4,849,664 f (after scans)
  float* v2b  = ws + 4849664;                        //  4,718,592 f -> ends 9,568,256
  float* wT   = ws + 9568256;                        //    552,960 f (after scan2)
  float* part = ws + 10121216;                       //  2,211,840 f -> ends 12,333,056
  __hip_bfloat16* h1b = (__hip_bfloat16*)(ws + 14745600);  // 19200x256 bf16
  float* h2   = ws + 17203200;                       //  4,915,200 f
  float* c_buf= ws + 17203200;                       // aliases h2 (dead before scan2 writes)
  float* out_ln = ws + 22118400;                     //  2,457,600 f
  __hip_bfloat16* A0b = (__hip_bfloat16*)(ws + 22118400);  // aliases out_ln
  __hip_bfloat16* W0b = (__hip_bfloat16*)(ws + 24576000);
  __hip_bfloat16* W1b = (__hip_bfloat16*)(ws + 24637440);
  float* v3   = ws + 24735744;                       //     30,720 f

  // 1. token softmax
  softmax_c_kernel<<<(M_TOK*8 + 255)/256, 256, 0, stream>>>(code, x, c_buf);
  // 2. embedding -> bf16 padded [19200][160]
  embed_bf16_kernel<<<(M_TOK*160 + 255)/256, 256, 0, stream>>>(c_buf, codebook, A0b, 160);
  // 2b. weight conversions
  convW_kernel<<<(768*160 + 255)/256, 256, 0, stream>>>(w_ih0, W0b, 768, 150, 160);
  convW_kernel<<<(768*256 + 255)/256, 256, 0, stream>>>(w_ih1, W1b, 768, 256, 256);
  // 3. gi layer0 (MFMA)
  gemm_mfma_kernel<<<dim3(6,150), 256, 0, stream>>>(A0b, W0b, b_ih0, gi, 160);
  // 4. scan layer0 -> h1 bf16
  gru_scan_kernel<__hip_bfloat16><<<256, 384, 0, stream>>>(gi, w_hh0, b_hh0, h1b, 256, (size_t)128);
  // 5. gi layer1 (MFMA)
  gemm_mfma_kernel<<<dim3(6,150), 256, 0, stream>>>(h1b, W1b, b_ih1, gi, 256);
  // 6. scan layer1 -> h2 fp32
  gru_scan_kernel<float><<<256, 384, 0, stream>>>(gi, w_hh1, b_hh1, h2, 128, (size_t)M_TOK*HIDN);
  // 7. ln0 -> out_ln [b][n][t][16]
  ln0_kernel<<<(B_SZ*8*L_SZ + 255)/256, 256, 0, stream>>>(h2, ln0g, ln0b, out_ln);
  // 8. caps conv1: NC=8, HIN=150, HOUT=74, S=2
  caps_conv_kernel<<<dim3(19,B_SZ), 128, 0, stream>>>(out_ln, w1, ln1g, ln1b, v1, 8, 150, 74, 2, 1.f/32.f);
  // 9. caps conv2: NC=32, HIN=74, HOUT=72, S=1
  caps_conv_kernel<<<dim3(18,B_SZ), 128, 0, stream>>>(v1, w2, ln2g, ln2b, v2b, 32, 74, 72, 1, 1.f/32.f);
  // 10. transpose wfc (gi region is dead now)
  transposeW_kernel<<<(NFC*240 + 255)/256, 256, 0, stream>>>(wfc, wT);
  // 11. pass A: uniform votes -> partials -> v3
  route_pass_kernel<0><<<dim3(NCH,B_SZ), 256, 0, stream>>>(v2b, wT, nullptr, part);
  reduce_v3_kernel<<<B_SZ, 240, 0, stream>>>(part, lnfg, lnfb, v3);
  // 12. pass C: softmax-routed -> partials -> LN -> norm head -> out
  route_pass_kernel<1><<<dim3(NCH,B_SZ), 256, 0, stream>>>(v2b, wT, v3, part);
  reduce_out_kernel<<<B_SZ, 240, 0, stream>>>(part, lnfg, lnfb, out);
}